// Round 1
// baseline (161.198 us; speedup 1.0000x reference)
//
#include <hip/hip_runtime.h>
#include <cstdint>
#include <cstddef>

#define BB 16
#define AA 8400
#define CC 80
#define MM 32
#define TOPK 13

// ---------------------------------------------------------------------------
// K1: per-(b,a) metrics: align = score * clip(ciou,0)^6, overlap = clip(ciou,0)
// stored as [B*M, A] rows (coalesced in a).
// ---------------------------------------------------------------------------
__global__ __launch_bounds__(256) void k_metrics(
    const float* __restrict__ pred_cls, const float* __restrict__ pred_bbox,
    const float* __restrict__ anchors, const int* __restrict__ gt_cls,
    const float* __restrict__ gt_bbox, const float* __restrict__ mask_gt,
    float* __restrict__ align_out, float* __restrict__ ovl_out)
{
  const int b = blockIdx.y;
  __shared__ float s_gx1[MM], s_gy1[MM], s_gx2[MM], s_gy2[MM], s_atan[MM], s_mgt[MM];
  __shared__ int s_lbl[MM];
  if (threadIdx.x < MM) {
    int m = threadIdx.x;
    float4 gb = reinterpret_cast<const float4*>(gt_bbox)[b*MM + m];
    s_gx1[m] = gb.x; s_gy1[m] = gb.y; s_gx2[m] = gb.z; s_gy2[m] = gb.w;
    float w1 = gb.z - gb.x, h1 = gb.w - gb.y + 1e-7f;
    s_atan[m] = atanf(w1 / h1);
    s_lbl[m] = gt_cls[b*MM + m];
    s_mgt[m] = mask_gt[b*MM + m];
  }
  __syncthreads();
  const int a = blockIdx.x*256 + threadIdx.x;
  if (a >= AA) return;
  const float2 xy = reinterpret_cast<const float2*>(anchors)[a];
  const float4 pb = reinterpret_cast<const float4*>(pred_bbox)[b*AA + a];
  const float w2 = pb.z - pb.x, h2 = pb.w - pb.y + 1e-7f;
  const float at2 = atanf(w2 / h2);
  const float* clsrow = pred_cls + ((size_t)(b*AA + a)) * CC;
  #pragma unroll 4
  for (int m = 0; m < MM; ++m) {
    const float gx1 = s_gx1[m], gy1 = s_gy1[m], gx2 = s_gx2[m], gy2 = s_gy2[m];
    const float mind = fminf(fminf(xy.x - gx1, xy.y - gy1),
                             fminf(gx2 - xy.x, gy2 - xy.y));
    float al = 0.f, ov = 0.f;
    if (mind > 1e-9f && s_mgt[m] > 0.f) {
      const float w1 = gx2 - gx1, h1 = gy2 - gy1 + 1e-7f;
      const float iw = fmaxf(fminf(gx2, pb.z) - fmaxf(gx1, pb.x), 0.f);
      const float ih = fmaxf(fminf(gy2, pb.w) - fmaxf(gy1, pb.y), 0.f);
      const float inter = iw * ih;
      const float uni = w1*h1 + w2*h2 - inter + 1e-7f;
      const float iou = inter / uni;
      const float cw = fmaxf(gx2, pb.z) - fminf(gx1, pb.x);
      const float ch = fmaxf(gy2, pb.w) - fminf(gy1, pb.y);
      const float c2 = cw*cw + ch*ch + 1e-7f;
      const float rx = pb.x + pb.z - gx1 - gx2;
      const float ry = pb.y + pb.w - gy1 - gy2;
      const float rho2 = (rx*rx + ry*ry) * 0.25f;
      const float dv = at2 - s_atan[m];
      const float v = 0.4052847345693511f * dv * dv;
      const float alpha = v / (v - iou + (1.f + 1e-7f));
      const float ciou = iou - (rho2 / c2 + v * alpha);
      ov = fmaxf(ciou, 0.f);
      const float o2 = ov * ov;
      al = clsrow[s_lbl[m]] * (o2 * o2 * o2);   // score * ov^6 (monotone == pow)
    }
    const size_t off = ((size_t)(b*MM + m)) * AA + a;
    align_out[off] = al;
    ovl_out[off]   = ov;
  }
}

// ---------------------------------------------------------------------------
// K2: per-(b,m) top-13 over A, tie = lower index first (jax.lax.top_k).
// One wave per (b,m). Selected anchors with mask_in_gts -> claim bit m.
// ---------------------------------------------------------------------------
__global__ __launch_bounds__(64) void k_topk(
    const float* __restrict__ align_in, const float* __restrict__ anchors,
    const float* __restrict__ gt_bbox, const float* __restrict__ mask_gt,
    unsigned int* __restrict__ claim)
{
  const int m = blockIdx.x, b = blockIdx.y;
  if (mask_gt[b*MM + m] <= 0.f) return;   // masked gt: contributes nothing
  const float* row = align_in + ((size_t)(b*MM + m)) * AA;
  const int lane = threadIdx.x;

  // per-lane top-13, sorted desc, ties: earlier (lower) index stays ahead
  float v[TOPK]; int id[TOPK];
  #pragma unroll
  for (int i = 0; i < TOPK; ++i) { v[i] = -1.f; id[i] = 0x7fffffff; }
  for (int a = lane; a < AA; a += 64) {
    const float val = row[a];   // >= 0 always
    if (val > v[TOPK-1]) {      // equal loses (higher index) -> skip
      #pragma unroll
      for (int i = TOPK-1; i >= 1; --i) {   // static-index shift network
        const bool ci = val > v[i];
        const bool cp = val > v[i-1];
        if (ci) {
          if (cp) { v[i] = v[i-1]; id[i] = id[i-1]; }
          else    { v[i] = val;    id[i] = a; }
        }
      }
      if (val > v[0]) { v[0] = val; id[0] = a; }
    }
  }

  const float4 gb = reinterpret_cast<const float4*>(gt_bbox)[b*MM + m];
  const unsigned int bit = 1u << m;
  for (int r = 0; r < TOPK; ++r) {
    float bv = v[0]; int bi = id[0];
    #pragma unroll
    for (int off = 32; off; off >>= 1) {
      const float ovv = __shfl_xor(bv, off);
      const int   oii = __shfl_xor(bi, off);
      if (ovv > bv || (ovv == bv && oii < bi)) { bv = ovv; bi = oii; }
    }
    // unique winner (indices are unique): that lane pops its head
    if (v[0] == bv && id[0] == bi) {
      #pragma unroll
      for (int i = 0; i < TOPK-1; ++i) { v[i] = v[i+1]; id[i] = id[i+1]; }
      v[TOPK-1] = -1.f; id[TOPK-1] = 0x7fffffff;
    }
    if (lane == 0) {
      const float2 xy = reinterpret_cast<const float2*>(anchors)[bi];
      const float mind = fminf(fminf(xy.x - gb.x, xy.y - gb.y),
                               fminf(gb.z - xy.x, gb.w - xy.y));
      if (mind > 1e-9f) atomicOr(&claim[b*AA + bi], bit);
    }
  }
}

// ---------------------------------------------------------------------------
// K3: per-anchor resolution: fg count, >1 -> argmax_m overlap (first max),
// write target_bbox + fg_mask, record assigned m + align, atomicMax pos_*.
// ---------------------------------------------------------------------------
__global__ __launch_bounds__(256) void k_resolve(
    const unsigned int* __restrict__ claim, const float* __restrict__ ovl,
    const float* __restrict__ align_in, const float* __restrict__ gt_bbox,
    float* __restrict__ out_bbox, float* __restrict__ out_fg,
    int* __restrict__ anchor_m, float* __restrict__ anchor_al,
    unsigned int* __restrict__ pos_align, unsigned int* __restrict__ pos_ovl)
{
  const int b = blockIdx.y;
  const int a = blockIdx.x*256 + threadIdx.x;
  if (a >= AA) return;
  const unsigned int cb = claim[b*AA + a];
  const int fg = __popc(cb);
  int asg = -1;
  if (fg == 1) {
    asg = __ffs(cb) - 1;
  } else if (fg > 1) {
    // is_max: argmax over ALL m of overlaps (first occurrence of max)
    float best = ovl[((size_t)(b*MM)) * AA + a];
    int bm = 0;
    for (int m = 1; m < MM; ++m) {
      const float o = ovl[((size_t)(b*MM + m)) * AA + a];
      if (o > best) { best = o; bm = m; }
    }
    asg = bm;
  }
  const int tgt = (asg >= 0) ? asg : 0;   // argmax of all-zero column = 0
  reinterpret_cast<float4*>(out_bbox)[b*AA + a] =
      reinterpret_cast<const float4*>(gt_bbox)[b*MM + tgt];
  out_fg[b*AA + a] = (asg >= 0) ? 1.f : 0.f;
  anchor_m[b*AA + a] = asg;
  float av = 0.f;
  if (asg >= 0) {
    const size_t off = ((size_t)(b*MM + asg)) * AA + a;
    av = align_in[off];
    atomicMax(&pos_align[b*MM + asg], __float_as_uint(av));           // >=0 floats
    atomicMax(&pos_ovl[b*MM + asg], __float_as_uint(ovl[off]));
  }
  anchor_al[b*AA + a] = av;
}

// ---------------------------------------------------------------------------
// K4: target_cls (B,A,C) float4-coalesced: norm at the label slot, else 0.
// ---------------------------------------------------------------------------
__global__ __launch_bounds__(256) void k_cls(
    const int* __restrict__ anchor_m, const float* __restrict__ anchor_al,
    const unsigned int* __restrict__ pos_align, const unsigned int* __restrict__ pos_ovl,
    const int* __restrict__ gt_cls, float* __restrict__ out_cls)
{
  const int tid = blockIdx.x*256 + threadIdx.x;
  if (tid >= BB*AA*(CC/4)) return;
  const int q  = tid % (CC/4);
  const int ba = tid / (CC/4);
  const int b  = ba / AA;
  const int m  = anchor_m[ba];
  float4 o = make_float4(0.f, 0.f, 0.f, 0.f);
  if (m >= 0) {
    const float pa = __uint_as_float(pos_align[b*MM + m]);
    const float po = __uint_as_float(pos_ovl[b*MM + m]);
    const float norm = anchor_al[ba] * po / (pa + 1e-9f);
    const int lbl = gt_cls[b*MM + m];
    const int c0 = q * 4;
    if (lbl == c0    ) o.x = norm;
    if (lbl == c0 + 1) o.y = norm;
    if (lbl == c0 + 2) o.z = norm;
    if (lbl == c0 + 3) o.w = norm;
  }
  reinterpret_cast<float4*>(out_cls)[tid] = o;
}

// ---------------------------------------------------------------------------
extern "C" void kernel_launch(void* const* d_in, const int* in_sizes, int n_in,
                              void* d_out, int out_size, void* d_ws, size_t ws_size,
                              hipStream_t stream)
{
  const float* pred_cls  = (const float*)d_in[0];
  const float* pred_bbox = (const float*)d_in[1];
  const float* anchors   = (const float*)d_in[2];
  const int*   gt_cls    = (const int*)  d_in[3];
  const float* gt_bbox   = (const float*)d_in[4];
  const float* mask_gt   = (const float*)d_in[5];

  // ws layout (all 16B-aligned offsets):
  //   claim      : B*A u32          @ 0          (537600 B)
  //   pos_align  : B*M u32(float)   @ 537600     (2048 B)
  //   pos_ovl    : B*M u32(float)   @ 539648     (2048 B)
  //   align      : B*M*A f32        @ 541696     (17203200 B)
  //   overlap    : B*M*A f32        @ 17744896   (17203200 B)
  //   anchor_m   : B*A i32          @ 34948096   (537600 B)
  //   anchor_al  : B*A f32          @ 35485696   (537600 B)
  // total 36023296 B (~34.4 MB)
  char* ws = (char*)d_ws;
  unsigned int* claim     = (unsigned int*)(ws);
  unsigned int* pos_align = (unsigned int*)(ws + 537600);
  unsigned int* pos_ovl   = (unsigned int*)(ws + 539648);
  float* align_buf = (float*)(ws + 541696);
  float* ovl_buf   = (float*)(ws + 17744896);
  int*   anchor_m  = (int*)  (ws + 34948096);
  float* anchor_al = (float*)(ws + 35485696);

  float* out_cls  = (float*)d_out;
  float* out_bbox = out_cls + (size_t)BB*AA*CC;
  float* out_fg   = out_bbox + (size_t)BB*AA*4;

  hipMemsetAsync(ws, 0, 541696, stream);   // claim + pos_align + pos_ovl

  k_metrics<<<dim3((AA + 255)/256, BB), 256, 0, stream>>>(
      pred_cls, pred_bbox, anchors, gt_cls, gt_bbox, mask_gt, align_buf, ovl_buf);
  k_topk<<<dim3(MM, BB), 64, 0, stream>>>(
      align_buf, anchors, gt_bbox, mask_gt, claim);
  k_resolve<<<dim3((AA + 255)/256, BB), 256, 0, stream>>>(
      claim, ovl_buf, align_buf, gt_bbox, out_bbox, out_fg,
      anchor_m, anchor_al, pos_align, pos_ovl);
  k_cls<<<(BB*AA*(CC/4) + 255)/256, 256, 0, stream>>>(
      anchor_m, anchor_al, pos_align, pos_ovl, gt_cls, out_cls);
}

// Round 2
// 88.967 us; speedup vs baseline: 1.8119x; 1.8119x over previous
//
#include <hip/hip_runtime.h>
#include <cstdint>
#include <cstddef>

#define BB 16
#define AA 8400
#define CC 80
#define MM 32
#define TOPK 13
#define NCH 16
#define CHSZ (AA / NCH)   // 525

// ---------------------------------------------------------------------------
// K1: per-(b,a) metrics: align = score * clip(ciou,0)^6, overlap = clip(ciou,0)
// stored as [B*M, A] rows (coalesced in a).
// ---------------------------------------------------------------------------
__global__ __launch_bounds__(256) void k_metrics(
    const float* __restrict__ pred_cls, const float* __restrict__ pred_bbox,
    const float* __restrict__ anchors, const int* __restrict__ gt_cls,
    const float* __restrict__ gt_bbox, const float* __restrict__ mask_gt,
    float* __restrict__ align_out, float* __restrict__ ovl_out)
{
  const int b = blockIdx.y;
  __shared__ float s_gx1[MM], s_gy1[MM], s_gx2[MM], s_gy2[MM], s_atan[MM], s_mgt[MM];
  __shared__ int s_lbl[MM];
  if (threadIdx.x < MM) {
    int m = threadIdx.x;
    float4 gb = reinterpret_cast<const float4*>(gt_bbox)[b*MM + m];
    s_gx1[m] = gb.x; s_gy1[m] = gb.y; s_gx2[m] = gb.z; s_gy2[m] = gb.w;
    float w1 = gb.z - gb.x, h1 = gb.w - gb.y + 1e-7f;
    s_atan[m] = atanf(w1 / h1);
    s_lbl[m] = gt_cls[b*MM + m];
    s_mgt[m] = mask_gt[b*MM + m];
  }
  __syncthreads();
  const int a = blockIdx.x*256 + threadIdx.x;
  if (a >= AA) return;
  const float2 xy = reinterpret_cast<const float2*>(anchors)[a];
  const float4 pb = reinterpret_cast<const float4*>(pred_bbox)[b*AA + a];
  const float w2 = pb.z - pb.x, h2 = pb.w - pb.y + 1e-7f;
  const float at2 = atanf(w2 / h2);
  const float* clsrow = pred_cls + ((size_t)(b*AA + a)) * CC;
  #pragma unroll 4
  for (int m = 0; m < MM; ++m) {
    const float gx1 = s_gx1[m], gy1 = s_gy1[m], gx2 = s_gx2[m], gy2 = s_gy2[m];
    const float mind = fminf(fminf(xy.x - gx1, xy.y - gy1),
                             fminf(gx2 - xy.x, gy2 - xy.y));
    float al = 0.f, ov = 0.f;
    if (mind > 1e-9f && s_mgt[m] > 0.f) {
      const float w1 = gx2 - gx1, h1 = gy2 - gy1 + 1e-7f;
      const float iw = fmaxf(fminf(gx2, pb.z) - fmaxf(gx1, pb.x), 0.f);
      const float ih = fmaxf(fminf(gy2, pb.w) - fmaxf(gy1, pb.y), 0.f);
      const float inter = iw * ih;
      const float uni = w1*h1 + w2*h2 - inter + 1e-7f;
      const float iou = inter / uni;
      const float cw = fmaxf(gx2, pb.z) - fminf(gx1, pb.x);
      const float ch = fmaxf(gy2, pb.w) - fminf(gy1, pb.y);
      const float c2 = cw*cw + ch*ch + 1e-7f;
      const float rx = pb.x + pb.z - gx1 - gx2;
      const float ry = pb.y + pb.w - gy1 - gy2;
      const float rho2 = (rx*rx + ry*ry) * 0.25f;
      const float dv = at2 - s_atan[m];
      const float v = 0.4052847345693511f * dv * dv;
      const float alpha = v / (v - iou + (1.f + 1e-7f));
      const float ciou = iou - (rho2 / c2 + v * alpha);
      ov = fmaxf(ciou, 0.f);
      const float o2 = ov * ov;
      al = clsrow[s_lbl[m]] * (o2 * o2 * o2);   // score * ov^6 (monotone == pow)
    }
    const size_t off = ((size_t)(b*MM + m)) * AA + a;
    align_out[off] = al;
    ovl_out[off]   = ov;
  }
}

// ---------------------------------------------------------------------------
// K2a: per-(b,m,chunk) exact top-13 of the 525-anchor chunk.
// Tie semantics: (val desc, idx asc) — matches jax.lax.top_k.
// ---------------------------------------------------------------------------
__global__ __launch_bounds__(64) void k_topk_p1(
    const float* __restrict__ align_in, const float* __restrict__ mask_gt,
    float* __restrict__ pvals, int* __restrict__ pidx)
{
  const int ch = blockIdx.x, m = blockIdx.y, b = blockIdx.z;
  if (mask_gt[b*MM + m] <= 0.f) return;   // masked gt: contributes nothing
  const float* row = align_in + ((size_t)(b*MM + m)) * AA;
  const int lane = threadIdx.x;

  // per-lane top-13, sorted desc, ties: earlier (lower) index stays ahead
  float v[TOPK]; int id[TOPK];
  #pragma unroll
  for (int i = 0; i < TOPK; ++i) { v[i] = -1.f; id[i] = 0x7fffffff; }
  const int a0 = ch * CHSZ, a1 = a0 + CHSZ;
  for (int a = a0 + lane; a < a1; a += 64) {
    const float val = row[a];   // >= 0 always
    if (val > v[TOPK-1]) {      // equal loses (higher index) -> skip
      #pragma unroll
      for (int i = TOPK-1; i >= 1; --i) {   // static-index shift network
        const bool ci = val > v[i];
        const bool cp = val > v[i-1];
        if (ci) {
          if (cp) { v[i] = v[i-1]; id[i] = id[i-1]; }
          else    { v[i] = val;    id[i] = a; }
        }
      }
      if (val > v[0]) { v[0] = val; id[0] = a; }
    }
  }

  float* pv = pvals + (((size_t)(b*MM + m))*NCH + ch) * TOPK;
  int*   pi = pidx  + (((size_t)(b*MM + m))*NCH + ch) * TOPK;
  for (int r = 0; r < TOPK; ++r) {
    float bv = v[0]; int bi = id[0];
    #pragma unroll
    for (int off = 32; off; off >>= 1) {
      const float ovv = __shfl_xor(bv, off);
      const int   oii = __shfl_xor(bi, off);
      if (ovv > bv || (ovv == bv && oii < bi)) { bv = ovv; bi = oii; }
    }
    if (v[0] == bv && id[0] == bi) {        // unique winner pops its head
      #pragma unroll
      for (int i = 0; i < TOPK-1; ++i) { v[i] = v[i+1]; id[i] = id[i+1]; }
      v[TOPK-1] = -1.f; id[TOPK-1] = 0x7fffffff;
    }
    if (lane == 0) { pv[r] = bv; pi[r] = bi; }
  }
}

// ---------------------------------------------------------------------------
// K2b: per-(b,m) merge of 16x13 = 208 candidates -> global top-13, then
// mask_in_gts check + claim-bit atomicOr. One wave per (b,m).
// ---------------------------------------------------------------------------
__global__ __launch_bounds__(64) void k_topk_p2(
    const float* __restrict__ pvals, const int* __restrict__ pidx,
    const float* __restrict__ anchors, const float* __restrict__ gt_bbox,
    const float* __restrict__ mask_gt, unsigned int* __restrict__ claim)
{
  const int m = blockIdx.x, b = blockIdx.y;
  if (mask_gt[b*MM + m] <= 0.f) return;
  const int lane = threadIdx.x;
  const float* pv = pvals + ((size_t)(b*MM + m)) * NCH * TOPK;
  const int*   pi = pidx  + ((size_t)(b*MM + m)) * NCH * TOPK;
  const int NC = NCH * TOPK;   // 208

  // 4 static slots per lane (rule #20: never dynamic-index these)
  float v0=-1.f, v1=-1.f, v2=-1.f, v3=-1.f;
  int   i0=0x7fffffff, i1=0x7fffffff, i2=0x7fffffff, i3=0x7fffffff;
  { int j;
    j = lane;        if (j < NC) { v0 = pv[j]; i0 = pi[j]; }
    j = lane + 64;   if (j < NC) { v1 = pv[j]; i1 = pi[j]; }
    j = lane + 128;  if (j < NC) { v2 = pv[j]; i2 = pi[j]; }
    j = lane + 192;  if (j < NC) { v3 = pv[j]; i3 = pi[j]; }
  }

  const float4 gb = reinterpret_cast<const float4*>(gt_bbox)[b*MM + m];
  const unsigned int bit = 1u << m;

  for (int r = 0; r < TOPK; ++r) {
    // lane-best among 4 slots (val desc, idx asc), remember slot statically
    float bv = v0; int bi = i0; int bs = 0;
    if (v1 > bv || (v1 == bv && i1 < bi)) { bv = v1; bi = i1; bs = 1; }
    if (v2 > bv || (v2 == bv && i2 < bi)) { bv = v2; bi = i2; bs = 2; }
    if (v3 > bv || (v3 == bv && i3 < bi)) { bv = v3; bi = i3; bs = 3; }
    const float myv = bv; const int myi = bi;
    #pragma unroll
    for (int off = 32; off; off >>= 1) {
      const float ovv = __shfl_xor(bv, off);
      const int   oii = __shfl_xor(bi, off);
      if (ovv > bv || (ovv == bv && oii < bi)) { bv = ovv; bi = oii; }
    }
    if (myv == bv && myi == bi) {           // winner lane clears its slot
      if (bs == 0) { v0 = -1.f; i0 = 0x7fffffff; }
      if (bs == 1) { v1 = -1.f; i1 = 0x7fffffff; }
      if (bs == 2) { v2 = -1.f; i2 = 0x7fffffff; }
      if (bs == 3) { v3 = -1.f; i3 = 0x7fffffff; }
    }
    if (lane == 0 && bi < AA) {
      const float2 xy = reinterpret_cast<const float2*>(anchors)[bi];
      const float mind = fminf(fminf(xy.x - gb.x, xy.y - gb.y),
                               fminf(gb.z - xy.x, gb.w - xy.y));
      if (mind > 1e-9f) atomicOr(&claim[b*AA + bi], bit);
    }
  }
}

// ---------------------------------------------------------------------------
// K3: per-anchor resolution: fg count, >1 -> argmax_m overlap (first max),
// write target_bbox + fg_mask, record assigned m + align, atomicMax pos_*.
// ---------------------------------------------------------------------------
__global__ __launch_bounds__(256) void k_resolve(
    const unsigned int* __restrict__ claim, const float* __restrict__ ovl,
    const float* __restrict__ align_in, const float* __restrict__ gt_bbox,
    float* __restrict__ out_bbox, float* __restrict__ out_fg,
    int* __restrict__ anchor_m, float* __restrict__ anchor_al,
    unsigned int* __restrict__ pos_align, unsigned int* __restrict__ pos_ovl)
{
  const int b = blockIdx.y;
  const int a = blockIdx.x*256 + threadIdx.x;
  if (a >= AA) return;
  const unsigned int cb = claim[b*AA + a];
  const int fg = __popc(cb);
  int asg = -1;
  if (fg == 1) {
    asg = __ffs(cb) - 1;
  } else if (fg > 1) {
    // is_max: argmax over ALL m of overlaps (first occurrence of max)
    float best = ovl[((size_t)(b*MM)) * AA + a];
    int bm = 0;
    for (int m = 1; m < MM; ++m) {
      const float o = ovl[((size_t)(b*MM + m)) * AA + a];
      if (o > best) { best = o; bm = m; }
    }
    asg = bm;
  }
  const int tgt = (asg >= 0) ? asg : 0;   // argmax of all-zero column = 0
  reinterpret_cast<float4*>(out_bbox)[b*AA + a] =
      reinterpret_cast<const float4*>(gt_bbox)[b*MM + tgt];
  out_fg[b*AA + a] = (asg >= 0) ? 1.f : 0.f;
  anchor_m[b*AA + a] = asg;
  float av = 0.f;
  if (asg >= 0) {
    const size_t off = ((size_t)(b*MM + asg)) * AA + a;
    av = align_in[off];
    atomicMax(&pos_align[b*MM + asg], __float_as_uint(av));           // >=0 floats
    atomicMax(&pos_ovl[b*MM + asg], __float_as_uint(ovl[off]));
  }
  anchor_al[b*AA + a] = av;
}

// ---------------------------------------------------------------------------
// K4: target_cls (B,A,C) float4-coalesced: norm at the label slot, else 0.
// ---------------------------------------------------------------------------
__global__ __launch_bounds__(256) void k_cls(
    const int* __restrict__ anchor_m, const float* __restrict__ anchor_al,
    const unsigned int* __restrict__ pos_align, const unsigned int* __restrict__ pos_ovl,
    const int* __restrict__ gt_cls, float* __restrict__ out_cls)
{
  const int tid = blockIdx.x*256 + threadIdx.x;
  if (tid >= BB*AA*(CC/4)) return;
  const int q  = tid % (CC/4);
  const int ba = tid / (CC/4);
  const int b  = ba / AA;
  const int m  = anchor_m[ba];
  float4 o = make_float4(0.f, 0.f, 0.f, 0.f);
  if (m >= 0) {
    const float pa = __uint_as_float(pos_align[b*MM + m]);
    const float po = __uint_as_float(pos_ovl[b*MM + m]);
    const float norm = anchor_al[ba] * po / (pa + 1e-9f);
    const int lbl = gt_cls[b*MM + m];
    const int c0 = q * 4;
    if (lbl == c0    ) o.x = norm;
    if (lbl == c0 + 1) o.y = norm;
    if (lbl == c0 + 2) o.z = norm;
    if (lbl == c0 + 3) o.w = norm;
  }
  reinterpret_cast<float4*>(out_cls)[tid] = o;
}

// ---------------------------------------------------------------------------
extern "C" void kernel_launch(void* const* d_in, const int* in_sizes, int n_in,
                              void* d_out, int out_size, void* d_ws, size_t ws_size,
                              hipStream_t stream)
{
  const float* pred_cls  = (const float*)d_in[0];
  const float* pred_bbox = (const float*)d_in[1];
  const float* anchors   = (const float*)d_in[2];
  const int*   gt_cls    = (const int*)  d_in[3];
  const float* gt_bbox   = (const float*)d_in[4];
  const float* mask_gt   = (const float*)d_in[5];

  // ws layout:
  //   claim      : B*A u32          @ 0          (537600 B)
  //   pos_align  : B*M u32(float)   @ 537600     (2048 B)
  //   pos_ovl    : B*M u32(float)   @ 539648     (2048 B)
  //   align      : B*M*A f32        @ 541696     (17203200 B)
  //   overlap    : B*M*A f32        @ 17744896   (17203200 B)
  //   anchor_m   : B*A i32          @ 34948096   (537600 B)
  //   anchor_al  : B*A f32          @ 35485696   (537600 B)
  //   pvals      : B*M*NCH*13 f32   @ 36023296   (425984 B)
  //   pidx       : B*M*NCH*13 i32   @ 36449280   (425984 B)
  // total 36875264 B (~35.2 MB)
  char* ws = (char*)d_ws;
  unsigned int* claim     = (unsigned int*)(ws);
  unsigned int* pos_align = (unsigned int*)(ws + 537600);
  unsigned int* pos_ovl   = (unsigned int*)(ws + 539648);
  float* align_buf = (float*)(ws + 541696);
  float* ovl_buf   = (float*)(ws + 17744896);
  int*   anchor_m  = (int*)  (ws + 34948096);
  float* anchor_al = (float*)(ws + 35485696);
  float* pvals     = (float*)(ws + 36023296);
  int*   pidx      = (int*)  (ws + 36449280);

  float* out_cls  = (float*)d_out;
  float* out_bbox = out_cls + (size_t)BB*AA*CC;
  float* out_fg   = out_bbox + (size_t)BB*AA*4;

  hipMemsetAsync(ws, 0, 541696, stream);   // claim + pos_align + pos_ovl

  k_metrics<<<dim3((AA + 255)/256, BB), 256, 0, stream>>>(
      pred_cls, pred_bbox, anchors, gt_cls, gt_bbox, mask_gt, align_buf, ovl_buf);
  k_topk_p1<<<dim3(NCH, MM, BB), 64, 0, stream>>>(
      align_buf, mask_gt, pvals, pidx);
  k_topk_p2<<<dim3(MM, BB), 64, 0, stream>>>(
      pvals, pidx, anchors, gt_bbox, mask_gt, claim);
  k_resolve<<<dim3((AA + 255)/256, BB), 256, 0, stream>>>(
      claim, ovl_buf, align_buf, gt_bbox, out_bbox, out_fg,
      anchor_m, anchor_al, pos_align, pos_ovl);
  k_cls<<<(BB*AA*(CC/4) + 255)/256, 256, 0, stream>>>(
      anchor_m, anchor_al, pos_align, pos_ovl, gt_cls, out_cls);
}

// Round 3
// 83.952 us; speedup vs baseline: 1.9201x; 1.0597x over previous
//
#include <hip/hip_runtime.h>
#include <cstdint>
#include <cstddef>

#define BB 16
#define AA 8400
#define CC 80
#define MM 32
#define TOPK 13
#define NCH 16
#define CHSZ (AA / NCH)   // 525

// ---------------------------------------------------------------------------
// K1: per-(b,a) metrics: align = score * clip(ciou,0)^6, overlap = clip(ciou,0)
// stored as [B*M, A] rows (coalesced in a). Also zero-inits claim/pos_* so no
// separate memset dispatch is needed (stream order covers the later readers).
// ---------------------------------------------------------------------------
__global__ __launch_bounds__(256) void k_metrics(
    const float* __restrict__ pred_cls, const float* __restrict__ pred_bbox,
    const float* __restrict__ anchors, const int* __restrict__ gt_cls,
    const float* __restrict__ gt_bbox, const float* __restrict__ mask_gt,
    float* __restrict__ align_out, float* __restrict__ ovl_out,
    unsigned int* __restrict__ claim,
    unsigned int* __restrict__ pos_align, unsigned int* __restrict__ pos_ovl)
{
  const int b = blockIdx.y;
  __shared__ float s_gx1[MM], s_gy1[MM], s_gx2[MM], s_gy2[MM], s_atan[MM], s_mgt[MM];
  __shared__ int s_lbl[MM];
  if (threadIdx.x < MM) {
    int m = threadIdx.x;
    float4 gb = reinterpret_cast<const float4*>(gt_bbox)[b*MM + m];
    s_gx1[m] = gb.x; s_gy1[m] = gb.y; s_gx2[m] = gb.z; s_gy2[m] = gb.w;
    float w1 = gb.z - gb.x, h1 = gb.w - gb.y + 1e-7f;
    s_atan[m] = atanf(w1 / h1);
    s_lbl[m] = gt_cls[b*MM + m];
    s_mgt[m] = mask_gt[b*MM + m];
    if (blockIdx.x == 0) {                 // zero pos_* (4 KB total)
      pos_align[b*MM + m] = 0u;
      pos_ovl[b*MM + m]   = 0u;
    }
  }
  __syncthreads();
  const int a = blockIdx.x*256 + threadIdx.x;
  if (a >= AA) return;
  claim[b*AA + a] = 0u;                    // zero claim (replaces memset)
  const float2 xy = reinterpret_cast<const float2*>(anchors)[a];
  const float4 pb = reinterpret_cast<const float4*>(pred_bbox)[b*AA + a];
  const float w2 = pb.z - pb.x, h2 = pb.w - pb.y + 1e-7f;
  const float at2 = atanf(w2 / h2);
  const float* clsrow = pred_cls + ((size_t)(b*AA + a)) * CC;
  #pragma unroll 4
  for (int m = 0; m < MM; ++m) {
    const float gx1 = s_gx1[m], gy1 = s_gy1[m], gx2 = s_gx2[m], gy2 = s_gy2[m];
    const float mind = fminf(fminf(xy.x - gx1, xy.y - gy1),
                             fminf(gx2 - xy.x, gy2 - xy.y));
    float al = 0.f, ov = 0.f;
    if (mind > 1e-9f && s_mgt[m] > 0.f) {
      const float w1 = gx2 - gx1, h1 = gy2 - gy1 + 1e-7f;
      const float iw = fmaxf(fminf(gx2, pb.z) - fmaxf(gx1, pb.x), 0.f);
      const float ih = fmaxf(fminf(gy2, pb.w) - fmaxf(gy1, pb.y), 0.f);
      const float inter = iw * ih;
      const float uni = w1*h1 + w2*h2 - inter + 1e-7f;
      const float iou = inter / uni;
      const float cw = fmaxf(gx2, pb.z) - fminf(gx1, pb.x);
      const float ch = fmaxf(gy2, pb.w) - fminf(gy1, pb.y);
      const float c2 = cw*cw + ch*ch + 1e-7f;
      const float rx = pb.x + pb.z - gx1 - gx2;
      const float ry = pb.y + pb.w - gy1 - gy2;
      const float rho2 = (rx*rx + ry*ry) * 0.25f;
      const float dv = at2 - s_atan[m];
      const float v = 0.4052847345693511f * dv * dv;
      const float alpha = v / (v - iou + (1.f + 1e-7f));
      const float ciou = iou - (rho2 / c2 + v * alpha);
      ov = fmaxf(ciou, 0.f);
      const float o2 = ov * ov;
      al = clsrow[s_lbl[m]] * (o2 * o2 * o2);   // score * ov^6 (monotone == pow)
    }
    const size_t off = ((size_t)(b*MM + m)) * AA + a;
    align_out[off] = al;
    ovl_out[off]   = ov;
  }
}

// ---------------------------------------------------------------------------
// K2a: per-(b,m,chunk) exact top-13 of the 525-anchor chunk.
// Tie semantics: (val desc, idx asc) — matches jax.lax.top_k.
// ---------------------------------------------------------------------------
__global__ __launch_bounds__(64) void k_topk_p1(
    const float* __restrict__ align_in, const float* __restrict__ mask_gt,
    float* __restrict__ pvals, int* __restrict__ pidx)
{
  const int ch = blockIdx.x, m = blockIdx.y, b = blockIdx.z;
  if (mask_gt[b*MM + m] <= 0.f) return;   // masked gt: contributes nothing
  const float* row = align_in + ((size_t)(b*MM + m)) * AA;
  const int lane = threadIdx.x;

  // per-lane top-13, sorted desc, ties: earlier (lower) index stays ahead
  float v[TOPK]; int id[TOPK];
  #pragma unroll
  for (int i = 0; i < TOPK; ++i) { v[i] = -1.f; id[i] = 0x7fffffff; }
  const int a0 = ch * CHSZ, a1 = a0 + CHSZ;
  for (int a = a0 + lane; a < a1; a += 64) {
    const float val = row[a];   // >= 0 always
    if (val > v[TOPK-1]) {      // equal loses (higher index) -> skip
      #pragma unroll
      for (int i = TOPK-1; i >= 1; --i) {   // static-index shift network
        const bool ci = val > v[i];
        const bool cp = val > v[i-1];
        if (ci) {
          if (cp) { v[i] = v[i-1]; id[i] = id[i-1]; }
          else    { v[i] = val;    id[i] = a; }
        }
      }
      if (val > v[0]) { v[0] = val; id[0] = a; }
    }
  }

  float* pv = pvals + (((size_t)(b*MM + m))*NCH + ch) * TOPK;
  int*   pi = pidx  + (((size_t)(b*MM + m))*NCH + ch) * TOPK;
  for (int r = 0; r < TOPK; ++r) {
    float bv = v[0]; int bi = id[0];
    #pragma unroll
    for (int off = 32; off; off >>= 1) {
      const float ovv = __shfl_xor(bv, off);
      const int   oii = __shfl_xor(bi, off);
      if (ovv > bv || (ovv == bv && oii < bi)) { bv = ovv; bi = oii; }
    }
    if (v[0] == bv && id[0] == bi) {        // unique winner pops its head
      #pragma unroll
      for (int i = 0; i < TOPK-1; ++i) { v[i] = v[i+1]; id[i] = id[i+1]; }
      v[TOPK-1] = -1.f; id[TOPK-1] = 0x7fffffff;
    }
    if (lane == 0) { pv[r] = bv; pi[r] = bi; }
  }
}

// ---------------------------------------------------------------------------
// K2b: per-(b,m) merge of 16x13 = 208 candidates -> global top-13, then
// mask_in_gts check + claim-bit atomicOr. One wave per (b,m).
// ---------------------------------------------------------------------------
__global__ __launch_bounds__(64) void k_topk_p2(
    const float* __restrict__ pvals, const int* __restrict__ pidx,
    const float* __restrict__ anchors, const float* __restrict__ gt_bbox,
    const float* __restrict__ mask_gt, unsigned int* __restrict__ claim)
{
  const int m = blockIdx.x, b = blockIdx.y;
  if (mask_gt[b*MM + m] <= 0.f) return;
  const int lane = threadIdx.x;
  const float* pv = pvals + ((size_t)(b*MM + m)) * NCH * TOPK;
  const int*   pi = pidx  + ((size_t)(b*MM + m)) * NCH * TOPK;
  const int NC = NCH * TOPK;   // 208

  // 4 static slots per lane (rule #20: never dynamic-index these)
  float v0=-1.f, v1=-1.f, v2=-1.f, v3=-1.f;
  int   i0=0x7fffffff, i1=0x7fffffff, i2=0x7fffffff, i3=0x7fffffff;
  { int j;
    j = lane;        if (j < NC) { v0 = pv[j]; i0 = pi[j]; }
    j = lane + 64;   if (j < NC) { v1 = pv[j]; i1 = pi[j]; }
    j = lane + 128;  if (j < NC) { v2 = pv[j]; i2 = pi[j]; }
    j = lane + 192;  if (j < NC) { v3 = pv[j]; i3 = pi[j]; }
  }

  const float4 gb = reinterpret_cast<const float4*>(gt_bbox)[b*MM + m];
  const unsigned int bit = 1u << m;

  for (int r = 0; r < TOPK; ++r) {
    // lane-best among 4 slots (val desc, idx asc), remember slot statically
    float bv = v0; int bi = i0; int bs = 0;
    if (v1 > bv || (v1 == bv && i1 < bi)) { bv = v1; bi = i1; bs = 1; }
    if (v2 > bv || (v2 == bv && i2 < bi)) { bv = v2; bi = i2; bs = 2; }
    if (v3 > bv || (v3 == bv && i3 < bi)) { bv = v3; bi = i3; bs = 3; }
    const float myv = bv; const int myi = bi;
    #pragma unroll
    for (int off = 32; off; off >>= 1) {
      const float ovv = __shfl_xor(bv, off);
      const int   oii = __shfl_xor(bi, off);
      if (ovv > bv || (ovv == bv && oii < bi)) { bv = ovv; bi = oii; }
    }
    if (myv == bv && myi == bi) {           // winner lane clears its slot
      if (bs == 0) { v0 = -1.f; i0 = 0x7fffffff; }
      if (bs == 1) { v1 = -1.f; i1 = 0x7fffffff; }
      if (bs == 2) { v2 = -1.f; i2 = 0x7fffffff; }
      if (bs == 3) { v3 = -1.f; i3 = 0x7fffffff; }
    }
    if (lane == 0 && bi < AA) {
      const float2 xy = reinterpret_cast<const float2*>(anchors)[bi];
      const float mind = fminf(fminf(xy.x - gb.x, xy.y - gb.y),
                               fminf(gb.z - xy.x, gb.w - xy.y));
      if (mind > 1e-9f) atomicOr(&claim[b*AA + bi], bit);
    }
  }
}

// ---------------------------------------------------------------------------
// K3: per-anchor resolution: fg count, >1 -> argmax_m overlap (first max),
// write target_bbox + fg_mask, record assigned m + align, atomicMax pos_*.
// ---------------------------------------------------------------------------
__global__ __launch_bounds__(256) void k_resolve(
    const unsigned int* __restrict__ claim, const float* __restrict__ ovl,
    const float* __restrict__ align_in, const float* __restrict__ gt_bbox,
    float* __restrict__ out_bbox, float* __restrict__ out_fg,
    int* __restrict__ anchor_m, float* __restrict__ anchor_al,
    unsigned int* __restrict__ pos_align, unsigned int* __restrict__ pos_ovl)
{
  const int b = blockIdx.y;
  const int a = blockIdx.x*256 + threadIdx.x;
  if (a >= AA) return;
  const unsigned int cb = claim[b*AA + a];
  const int fg = __popc(cb);
  int asg = -1;
  if (fg == 1) {
    asg = __ffs(cb) - 1;
  } else if (fg > 1) {
    // is_max: argmax over ALL m of overlaps (first occurrence of max)
    float best = ovl[((size_t)(b*MM)) * AA + a];
    int bm = 0;
    for (int m = 1; m < MM; ++m) {
      const float o = ovl[((size_t)(b*MM + m)) * AA + a];
      if (o > best) { best = o; bm = m; }
    }
    asg = bm;
  }
  const int tgt = (asg >= 0) ? asg : 0;   // argmax of all-zero column = 0
  reinterpret_cast<float4*>(out_bbox)[b*AA + a] =
      reinterpret_cast<const float4*>(gt_bbox)[b*MM + tgt];
  out_fg[b*AA + a] = (asg >= 0) ? 1.f : 0.f;
  anchor_m[b*AA + a] = asg;
  float av = 0.f;
  if (asg >= 0) {
    const size_t off = ((size_t)(b*MM + asg)) * AA + a;
    av = align_in[off];
    atomicMax(&pos_align[b*MM + asg], __float_as_uint(av));           // >=0 floats
    atomicMax(&pos_ovl[b*MM + asg], __float_as_uint(ovl[off]));
  }
  anchor_al[b*AA + a] = av;
}

// ---------------------------------------------------------------------------
// K4: target_cls (B,A,C) float4-coalesced: norm at the label slot, else 0.
// ---------------------------------------------------------------------------
__global__ __launch_bounds__(256) void k_cls(
    const int* __restrict__ anchor_m, const float* __restrict__ anchor_al,
    const unsigned int* __restrict__ pos_align, const unsigned int* __restrict__ pos_ovl,
    const int* __restrict__ gt_cls, float* __restrict__ out_cls)
{
  const int tid = blockIdx.x*256 + threadIdx.x;
  if (tid >= BB*AA*(CC/4)) return;
  const int q  = tid % (CC/4);
  const int ba = tid / (CC/4);
  const int b  = ba / AA;
  const int m  = anchor_m[ba];
  float4 o = make_float4(0.f, 0.f, 0.f, 0.f);
  if (m >= 0) {
    const float pa = __uint_as_float(pos_align[b*MM + m]);
    const float po = __uint_as_float(pos_ovl[b*MM + m]);
    const float norm = anchor_al[ba] * po / (pa + 1e-9f);
    const int lbl = gt_cls[b*MM + m];
    const int c0 = q * 4;
    if (lbl == c0    ) o.x = norm;
    if (lbl == c0 + 1) o.y = norm;
    if (lbl == c0 + 2) o.z = norm;
    if (lbl == c0 + 3) o.w = norm;
  }
  reinterpret_cast<float4*>(out_cls)[tid] = o;
}

// ---------------------------------------------------------------------------
extern "C" void kernel_launch(void* const* d_in, const int* in_sizes, int n_in,
                              void* d_out, int out_size, void* d_ws, size_t ws_size,
                              hipStream_t stream)
{
  const float* pred_cls  = (const float*)d_in[0];
  const float* pred_bbox = (const float*)d_in[1];
  const float* anchors   = (const float*)d_in[2];
  const int*   gt_cls    = (const int*)  d_in[3];
  const float* gt_bbox   = (const float*)d_in[4];
  const float* mask_gt   = (const float*)d_in[5];

  // ws layout:
  //   claim      : B*A u32          @ 0          (537600 B)
  //   pos_align  : B*M u32(float)   @ 537600     (2048 B)
  //   pos_ovl    : B*M u32(float)   @ 539648     (2048 B)
  //   align      : B*M*A f32        @ 541696     (17203200 B)
  //   overlap    : B*M*A f32        @ 17744896   (17203200 B)
  //   anchor_m   : B*A i32          @ 34948096   (537600 B)
  //   anchor_al  : B*A f32          @ 35485696   (537600 B)
  //   pvals      : B*M*NCH*13 f32   @ 36023296   (425984 B)
  //   pidx       : B*M*NCH*13 i32   @ 36449280   (425984 B)
  // total 36875264 B (~35.2 MB)
  char* ws = (char*)d_ws;
  unsigned int* claim     = (unsigned int*)(ws);
  unsigned int* pos_align = (unsigned int*)(ws + 537600);
  unsigned int* pos_ovl   = (unsigned int*)(ws + 539648);
  float* align_buf = (float*)(ws + 541696);
  float* ovl_buf   = (float*)(ws + 17744896);
  int*   anchor_m  = (int*)  (ws + 34948096);
  float* anchor_al = (float*)(ws + 35485696);
  float* pvals     = (float*)(ws + 36023296);
  int*   pidx      = (int*)  (ws + 36449280);

  float* out_cls  = (float*)d_out;
  float* out_bbox = out_cls + (size_t)BB*AA*CC;
  float* out_fg   = out_bbox + (size_t)BB*AA*4;

  k_metrics<<<dim3((AA + 255)/256, BB), 256, 0, stream>>>(
      pred_cls, pred_bbox, anchors, gt_cls, gt_bbox, mask_gt,
      align_buf, ovl_buf, claim, pos_align, pos_ovl);
  k_topk_p1<<<dim3(NCH, MM, BB), 64, 0, stream>>>(
      align_buf, mask_gt, pvals, pidx);
  k_topk_p2<<<dim3(MM, BB), 64, 0, stream>>>(
      pvals, pidx, anchors, gt_bbox, mask_gt, claim);
  k_resolve<<<dim3((AA + 255)/256, BB), 256, 0, stream>>>(
      claim, ovl_buf, align_buf, gt_bbox, out_bbox, out_fg,
      anchor_m, anchor_al, pos_align, pos_ovl);
  k_cls<<<(BB*AA*(CC/4) + 255)/256, 256, 0, stream>>>(
      anchor_m, anchor_al, pos_align, pos_ovl, gt_cls, out_cls);
}

// Round 4
// 73.462 us; speedup vs baseline: 2.1943x; 1.1428x over previous
//
#include <hip/hip_runtime.h>
#include <cstdint>
#include <cstddef>

#define BB 16
#define AA 8400
#define CC 80
#define MM 32
#define TOPK 13
#define NCH 16
#define CHSZ (AA / NCH)   // 525

// Shared CIoU (clipped) so every use site has the identical formula.
__device__ __forceinline__ float ciou_clip(
    float gx1, float gy1, float gx2, float gy2, float at1,
    float4 pb, float w2, float h2, float at2)
{
  const float w1 = gx2 - gx1, h1 = gy2 - gy1 + 1e-7f;
  const float iw = fmaxf(fminf(gx2, pb.z) - fmaxf(gx1, pb.x), 0.f);
  const float ih = fmaxf(fminf(gy2, pb.w) - fmaxf(gy1, pb.y), 0.f);
  const float inter = iw * ih;
  const float uni = w1*h1 + w2*h2 - inter + 1e-7f;
  const float iou = inter / uni;
  const float cw = fmaxf(gx2, pb.z) - fminf(gx1, pb.x);
  const float ch = fmaxf(gy2, pb.w) - fminf(gy1, pb.y);
  const float c2 = cw*cw + ch*ch + 1e-7f;
  const float rx = pb.x + pb.z - gx1 - gx2;
  const float ry = pb.y + pb.w - gy1 - gy2;
  const float rho2 = (rx*rx + ry*ry) * 0.25f;
  const float dv = at2 - at1;
  const float v = 0.4052847345693511f * dv * dv;
  const float alpha = v / (v - iou + (1.f + 1e-7f));
  return fmaxf(iou - (rho2 / c2 + v * alpha), 0.f);
}

// ---------------------------------------------------------------------------
// K1 (fused): per-(b,m,chunk) compute align on the fly and keep exact top-13
// of the 525-anchor chunk in registers. No align/ovl buffers materialized.
// Also zero-inits claim (m==0 blocks) and pos_* (m==0,ch==0 block).
// Tie semantics: (val desc, idx asc) — matches jax.lax.top_k.
// ---------------------------------------------------------------------------
__global__ __launch_bounds__(64) void k_metrics_topk(
    const float* __restrict__ pred_cls, const float* __restrict__ pred_bbox,
    const float* __restrict__ anchors, const int* __restrict__ gt_cls,
    const float* __restrict__ gt_bbox, const float* __restrict__ mask_gt,
    float* __restrict__ pvals, int* __restrict__ pidx,
    unsigned int* __restrict__ claim,
    unsigned int* __restrict__ pos_align, unsigned int* __restrict__ pos_ovl)
{
  const int ch = blockIdx.x, m = blockIdx.y, b = blockIdx.z;
  const int lane = threadIdx.x;

  if (m == 0) {                            // zero-init duty (replaces memset)
    for (int i = lane; i < CHSZ; i += 64) claim[b*AA + ch*CHSZ + i] = 0u;
    if (ch == 0 && lane < MM) { pos_align[b*MM + lane] = 0u; pos_ovl[b*MM + lane] = 0u; }
  }
  if (mask_gt[b*MM + m] <= 0.f) return;    // masked gt: contributes nothing

  const float4 gb = reinterpret_cast<const float4*>(gt_bbox)[b*MM + m];
  const float gw = gb.z - gb.x, gh = gb.w - gb.y + 1e-7f;
  const float at1 = atanf(gw / gh);
  const int lbl = gt_cls[b*MM + m];
  const float* clsbase = pred_cls + (size_t)b*AA*CC;
  const float4* pbase  = reinterpret_cast<const float4*>(pred_bbox) + (size_t)b*AA;

  // per-lane top-13, sorted desc, ties: earlier (lower) index stays ahead
  float v[TOPK]; int id[TOPK];
  #pragma unroll
  for (int i = 0; i < TOPK; ++i) { v[i] = -1.f; id[i] = 0x7fffffff; }

  const int a0 = ch * CHSZ;
  for (int a = a0 + lane; a < a0 + CHSZ; a += 64) {
    const float2 xy = reinterpret_cast<const float2*>(anchors)[a];
    const float mind = fminf(fminf(xy.x - gb.x, xy.y - gb.y),
                             fminf(gb.z - xy.x, gb.w - xy.y));
    float val = 0.f;
    if (mind > 1e-9f) {
      const float4 pb = pbase[a];
      const float w2 = pb.z - pb.x, h2 = pb.w - pb.y + 1e-7f;
      const float at2 = atanf(w2 / h2);
      const float ov = ciou_clip(gb.x, gb.y, gb.z, gb.w, at1, pb, w2, h2, at2);
      const float o2 = ov * ov;
      val = clsbase[(size_t)a*CC + lbl] * (o2 * o2 * o2);  // score * ov^6
    }
    if (val > v[TOPK-1]) {      // equal loses (higher index) -> skip
      #pragma unroll
      for (int i = TOPK-1; i >= 1; --i) {   // static-index shift network
        const bool ci = val > v[i];
        const bool cp = val > v[i-1];
        if (ci) {
          if (cp) { v[i] = v[i-1]; id[i] = id[i-1]; }
          else    { v[i] = val;    id[i] = a; }
        }
      }
      if (val > v[0]) { v[0] = val; id[0] = a; }
    }
  }

  float* pv = pvals + (((size_t)(b*MM + m))*NCH + ch) * TOPK;
  int*   pi = pidx  + (((size_t)(b*MM + m))*NCH + ch) * TOPK;
  for (int r = 0; r < TOPK; ++r) {
    float bv = v[0]; int bi = id[0];
    #pragma unroll
    for (int off = 32; off; off >>= 1) {
      const float ovv = __shfl_xor(bv, off);
      const int   oii = __shfl_xor(bi, off);
      if (ovv > bv || (ovv == bv && oii < bi)) { bv = ovv; bi = oii; }
    }
    if (v[0] == bv && id[0] == bi) {        // unique winner pops its head
      #pragma unroll
      for (int i = 0; i < TOPK-1; ++i) { v[i] = v[i+1]; id[i] = id[i+1]; }
      v[TOPK-1] = -1.f; id[TOPK-1] = 0x7fffffff;
    }
    if (lane == 0) { pv[r] = bv; pi[r] = bi; }
  }
}

// ---------------------------------------------------------------------------
// K2: per-(b,m) merge of 16x13 = 208 candidates -> global top-13, then
// mask_in_gts check + claim-bit atomicOr. One wave per (b,m).
// ---------------------------------------------------------------------------
__global__ __launch_bounds__(64) void k_topk_p2(
    const float* __restrict__ pvals, const int* __restrict__ pidx,
    const float* __restrict__ anchors, const float* __restrict__ gt_bbox,
    const float* __restrict__ mask_gt, unsigned int* __restrict__ claim)
{
  const int m = blockIdx.x, b = blockIdx.y;
  if (mask_gt[b*MM + m] <= 0.f) return;
  const int lane = threadIdx.x;
  const float* pv = pvals + ((size_t)(b*MM + m)) * NCH * TOPK;
  const int*   pi = pidx  + ((size_t)(b*MM + m)) * NCH * TOPK;
  const int NC = NCH * TOPK;   // 208

  // 4 static slots per lane (rule #20: never dynamic-index these)
  float v0=-1.f, v1=-1.f, v2=-1.f, v3=-1.f;
  int   i0=0x7fffffff, i1=0x7fffffff, i2=0x7fffffff, i3=0x7fffffff;
  { int j;
    j = lane;        if (j < NC) { v0 = pv[j]; i0 = pi[j]; }
    j = lane + 64;   if (j < NC) { v1 = pv[j]; i1 = pi[j]; }
    j = lane + 128;  if (j < NC) { v2 = pv[j]; i2 = pi[j]; }
    j = lane + 192;  if (j < NC) { v3 = pv[j]; i3 = pi[j]; }
  }

  const float4 gb = reinterpret_cast<const float4*>(gt_bbox)[b*MM + m];
  const unsigned int bit = 1u << m;

  for (int r = 0; r < TOPK; ++r) {
    float bv = v0; int bi = i0; int bs = 0;
    if (v1 > bv || (v1 == bv && i1 < bi)) { bv = v1; bi = i1; bs = 1; }
    if (v2 > bv || (v2 == bv && i2 < bi)) { bv = v2; bi = i2; bs = 2; }
    if (v3 > bv || (v3 == bv && i3 < bi)) { bv = v3; bi = i3; bs = 3; }
    const float myv = bv; const int myi = bi;
    #pragma unroll
    for (int off = 32; off; off >>= 1) {
      const float ovv = __shfl_xor(bv, off);
      const int   oii = __shfl_xor(bi, off);
      if (ovv > bv || (ovv == bv && oii < bi)) { bv = ovv; bi = oii; }
    }
    if (myv == bv && myi == bi) {           // winner lane clears its slot
      if (bs == 0) { v0 = -1.f; i0 = 0x7fffffff; }
      if (bs == 1) { v1 = -1.f; i1 = 0x7fffffff; }
      if (bs == 2) { v2 = -1.f; i2 = 0x7fffffff; }
      if (bs == 3) { v3 = -1.f; i3 = 0x7fffffff; }
    }
    if (lane == 0 && bi < AA) {
      const float2 xy = reinterpret_cast<const float2*>(anchors)[bi];
      const float mind = fminf(fminf(xy.x - gb.x, xy.y - gb.y),
                               fminf(gb.z - xy.x, gb.w - xy.y));
      if (mind > 1e-9f) atomicOr(&claim[b*AA + bi], bit);
    }
  }
}

// ---------------------------------------------------------------------------
// K3: per-anchor resolution with sparse CIoU recompute. fg==1 -> claiming m;
// fg>1 -> first-max argmax_m of masked overlaps (recomputed). Writes
// target_bbox + fg_mask + anchor_m/al; atomicMax pos_align/pos_ovl.
// ---------------------------------------------------------------------------
__global__ __launch_bounds__(256) void k_resolve(
    const float* __restrict__ pred_cls, const float* __restrict__ pred_bbox,
    const float* __restrict__ anchors, const int* __restrict__ gt_cls,
    const float* __restrict__ gt_bbox, const float* __restrict__ mask_gt,
    const unsigned int* __restrict__ claim,
    float* __restrict__ out_bbox, float* __restrict__ out_fg,
    int* __restrict__ anchor_m, float* __restrict__ anchor_al,
    unsigned int* __restrict__ pos_align, unsigned int* __restrict__ pos_ovl)
{
  const int b = blockIdx.y;
  __shared__ float s_x1[MM], s_y1[MM], s_x2[MM], s_y2[MM], s_at[MM], s_mgt[MM];
  __shared__ int s_lbl[MM];
  if (threadIdx.x < MM) {
    int m = threadIdx.x;
    float4 g = reinterpret_cast<const float4*>(gt_bbox)[b*MM + m];
    s_x1[m] = g.x; s_y1[m] = g.y; s_x2[m] = g.z; s_y2[m] = g.w;
    s_at[m] = atanf((g.z - g.x) / (g.w - g.y + 1e-7f));
    s_lbl[m] = gt_cls[b*MM + m];
    s_mgt[m] = mask_gt[b*MM + m];
  }
  __syncthreads();
  const int a = blockIdx.x*256 + threadIdx.x;
  if (a >= AA) return;
  const unsigned int cb = claim[b*AA + a];
  const int fg = __popc(cb);
  int asg = -1; float bestov = 0.f;
  if (fg > 0) {
    const float4 pb = reinterpret_cast<const float4*>(pred_bbox)[b*AA + a];
    const float2 xy = reinterpret_cast<const float2*>(anchors)[a];
    const float w2 = pb.z - pb.x, h2 = pb.w - pb.y + 1e-7f;
    const float at2 = atanf(w2 / h2);
    if (fg == 1) {
      asg = __ffs(cb) - 1;   // claimed => in-gts && mask_gt>0 already hold
      bestov = ciou_clip(s_x1[asg], s_y1[asg], s_x2[asg], s_y2[asg], s_at[asg],
                         pb, w2, h2, at2);
    } else {
      // is_max: first argmax over ALL m of masked overlaps
      float best = -1.f; int bm = 0;
      for (int m = 0; m < MM; ++m) {
        float ov = 0.f;
        const float mind = fminf(fminf(xy.x - s_x1[m], xy.y - s_y1[m]),
                                 fminf(s_x2[m] - xy.x, s_y2[m] - xy.y));
        if (mind > 1e-9f && s_mgt[m] > 0.f)
          ov = ciou_clip(s_x1[m], s_y1[m], s_x2[m], s_y2[m], s_at[m],
                         pb, w2, h2, at2);
        if (ov > best) { best = ov; bm = m; }   // strict > => first max
      }
      asg = bm; bestov = best;
    }
  }
  const int tgt = (asg >= 0) ? asg : 0;   // argmax of all-zero column = 0
  float4 tb; tb.x = s_x1[tgt]; tb.y = s_y1[tgt]; tb.z = s_x2[tgt]; tb.w = s_y2[tgt];
  reinterpret_cast<float4*>(out_bbox)[b*AA + a] = tb;
  out_fg[b*AA + a] = (asg >= 0) ? 1.f : 0.f;
  anchor_m[b*AA + a] = asg;
  float av = 0.f;
  if (asg >= 0) {
    const float o2 = bestov * bestov;
    av = pred_cls[(size_t)(b*AA + a)*CC + s_lbl[asg]] * (o2 * o2 * o2);
    atomicMax(&pos_align[b*MM + asg], __float_as_uint(av));    // >=0 floats
    atomicMax(&pos_ovl[b*MM + asg], __float_as_uint(bestov));
  }
  anchor_al[b*AA + a] = av;
}

// ---------------------------------------------------------------------------
// K4: target_cls (B,A,C) float4-coalesced: norm at the label slot, else 0.
// ---------------------------------------------------------------------------
__global__ __launch_bounds__(256) void k_cls(
    const int* __restrict__ anchor_m, const float* __restrict__ anchor_al,
    const unsigned int* __restrict__ pos_align, const unsigned int* __restrict__ pos_ovl,
    const int* __restrict__ gt_cls, float* __restrict__ out_cls)
{
  const int tid = blockIdx.x*256 + threadIdx.x;
  if (tid >= BB*AA*(CC/4)) return;
  const int q  = tid % (CC/4);
  const int ba = tid / (CC/4);
  const int b  = ba / AA;
  const int m  = anchor_m[ba];
  float4 o = make_float4(0.f, 0.f, 0.f, 0.f);
  if (m >= 0) {
    const float pa = __uint_as_float(pos_align[b*MM + m]);
    const float po = __uint_as_float(pos_ovl[b*MM + m]);
    const float norm = anchor_al[ba] * po / (pa + 1e-9f);
    const int lbl = gt_cls[b*MM + m];
    const int c0 = q * 4;
    if (lbl == c0    ) o.x = norm;
    if (lbl == c0 + 1) o.y = norm;
    if (lbl == c0 + 2) o.z = norm;
    if (lbl == c0 + 3) o.w = norm;
  }
  reinterpret_cast<float4*>(out_cls)[tid] = o;
}

// ---------------------------------------------------------------------------
extern "C" void kernel_launch(void* const* d_in, const int* in_sizes, int n_in,
                              void* d_out, int out_size, void* d_ws, size_t ws_size,
                              hipStream_t stream)
{
  const float* pred_cls  = (const float*)d_in[0];
  const float* pred_bbox = (const float*)d_in[1];
  const float* anchors   = (const float*)d_in[2];
  const int*   gt_cls    = (const int*)  d_in[3];
  const float* gt_bbox   = (const float*)d_in[4];
  const float* mask_gt   = (const float*)d_in[5];

  // ws layout:
  //   claim      : B*A u32          @ 0          (537600 B)
  //   pos_align  : B*M u32(float)   @ 537600     (2048 B)
  //   pos_ovl    : B*M u32(float)   @ 539648     (2048 B)
  //   anchor_m   : B*A i32          @ 541696     (537600 B)
  //   anchor_al  : B*A f32          @ 1079296    (537600 B)
  //   pvals      : B*M*NCH*13 f32   @ 1616896    (425984 B)
  //   pidx       : B*M*NCH*13 i32   @ 2042880    (425984 B)
  // total 2468864 B (~2.4 MB)
  char* ws = (char*)d_ws;
  unsigned int* claim     = (unsigned int*)(ws);
  unsigned int* pos_align = (unsigned int*)(ws + 537600);
  unsigned int* pos_ovl   = (unsigned int*)(ws + 539648);
  int*   anchor_m  = (int*)  (ws + 541696);
  float* anchor_al = (float*)(ws + 1079296);
  float* pvals     = (float*)(ws + 1616896);
  int*   pidx      = (int*)  (ws + 2042880);

  float* out_cls  = (float*)d_out;
  float* out_bbox = out_cls + (size_t)BB*AA*CC;
  float* out_fg   = out_bbox + (size_t)BB*AA*4;

  k_metrics_topk<<<dim3(NCH, MM, BB), 64, 0, stream>>>(
      pred_cls, pred_bbox, anchors, gt_cls, gt_bbox, mask_gt,
      pvals, pidx, claim, pos_align, pos_ovl);
  k_topk_p2<<<dim3(MM, BB), 64, 0, stream>>>(
      pvals, pidx, anchors, gt_bbox, mask_gt, claim);
  k_resolve<<<dim3((AA + 255)/256, BB), 256, 0, stream>>>(
      pred_cls, pred_bbox, anchors, gt_cls, gt_bbox, mask_gt, claim,
      out_bbox, out_fg, anchor_m, anchor_al, pos_align, pos_ovl);
  k_cls<<<(BB*AA*(CC/4) + 255)/256, 256, 0, stream>>>(
      anchor_m, anchor_al, pos_align, pos_ovl, gt_cls, out_cls);
}